// Round 1
// baseline (1833.917 us; speedup 1.0000x reference)
//
#include <hip/hip_runtime.h>
#include <hip/hip_bf16.h>

typedef __attribute__((ext_vector_type(8))) short short8;
typedef __attribute__((ext_vector_type(4))) float f32x4;
typedef unsigned short u16;

#define IN_C 128
#define OUT_C 256
#define LN_EPS 1e-5f

__device__ __forceinline__ u16 f2bf(float f) {
    __hip_bfloat16 h = __float2bfloat16(f);
    return __builtin_bit_cast(u16, h);
}

// deg[i] = 1.0 (self loop)
__global__ void k_init_deg(float* __restrict__ deg, int n) {
    int i = blockIdx.x * 256 + threadIdx.x;
    if (i < n) deg[i] = 1.0f;
}

// deg[col[e]] += ew[e % 32]
__global__ void k_edge_deg(const int* __restrict__ ei, const float* __restrict__ ew,
                           float* __restrict__ deg, int E) {
    int e = blockIdx.x * 256 + threadIdx.x;
    if (e < E) atomicAdd(&deg[ei[E + e]], ew[e & 31]);
}

// deg -> rsqrt(deg) in place
__global__ void k_dinv(float* __restrict__ deg, int n) {
    int i = blockIdx.x * 256 + threadIdx.x;
    if (i < n) deg[i] = rsqrtf(deg[i]);
}

// Pack Wc = [W_gcn ; W_res] (256x256) into MFMA B-fragment order (bf16) and bc = b_gcn + b_res.
// frag layout: element ((s*16 + t)*64 + lane)*8 + j  ==  Wc[k = s*32 + (lane>>4)*8 + j][n = t*16 + (lane&15)]
__global__ void k_wprep(const float* __restrict__ Wg, const float* __restrict__ Wr,
                        const float* __restrict__ bg, const float* __restrict__ br,
                        u16* __restrict__ wfrag, float* __restrict__ bc) {
    int tid = blockIdx.x * 256 + threadIdx.x;
    if (tid < OUT_C) bc[tid] = bg[tid] + br[tid];
    if (tid >= 8192) return;
    int l = tid & 63;
    int t = (tid >> 6) & 15;
    int s = tid >> 10;
    int n = t * 16 + (l & 15);
    int k0 = s * 32 + (l >> 4) * 8;
    short8 pk;
#pragma unroll
    for (int j = 0; j < 8; ++j) {
        int k = k0 + j;
        float w = (k < IN_C) ? Wg[k * OUT_C + n] : Wr[(k - IN_C) * OUT_C + n];
        pk[j] = (short)f2bf(w);
    }
    reinterpret_cast<short8*>(wfrag)[tid] = pk;
}

// per edge: S[col] += norm * x[row]   (32 lanes/edge, float4 per lane)
__global__ void k_scatter(const int* __restrict__ ei, const float* __restrict__ ew,
                          const float* __restrict__ dinv, const float4* __restrict__ x4,
                          float* __restrict__ S, int E) {
    int gid = blockIdx.x * 256 + threadIdx.x;
    int e = gid >> 5;
    if (e >= E) return;
    int c = gid & 31;
    int r = ei[e];
    int col = ei[E + e];
    float nrm = dinv[r] * ew[e & 31] * dinv[col];
    float4 v = x4[(size_t)r * 32 + c];
    float* sp = S + (size_t)col * IN_C + c * 4;
    atomicAdd(sp + 0, nrm * v.x);
    atomicAdd(sp + 1, nrm * v.y);
    atomicAdd(sp + 2, nrm * v.z);
    atomicAdd(sp + 3, nrm * v.w);
}

// Fused: h = [u | x] @ Wc + bc ; LayerNorm(h)*gamma+beta ; relu ; store.
// u = S + x*dinv^2. BM=64 rows/block, 4 waves x (16 rows x 256 cols) each.
__global__ __launch_bounds__(256) void k_gemm(
    const float4* __restrict__ S4, const float4* __restrict__ x4,
    const float* __restrict__ dinv, const u16* __restrict__ wfrag,
    const float* __restrict__ bc, const float* __restrict__ gamma,
    const float* __restrict__ beta, float* __restrict__ out, int N) {

    __shared__ u16 A[64 * 264];  // [64 rows][256 bf16 + 8 pad] : cols 0..127 = u, 128..255 = x
    const int tid = threadIdx.x;
    const int lane = tid & 63;
    const int wave = tid >> 6;
    const long r0 = (long)blockIdx.x * 64;

    // stage A-tile: 64 rows x 128 float4-pairs, compute u, cast bf16
#pragma unroll
    for (int i = 0; i < 8; ++i) {
        int idx = tid + i * 256;
        int row = idx >> 5;
        int c4 = idx & 31;
        long gr = r0 + row;
        float4 sv = make_float4(0.f, 0.f, 0.f, 0.f);
        float4 xv = make_float4(0.f, 0.f, 0.f, 0.f);
        float d2 = 0.f;
        if (gr < N) {
            sv = S4[gr * 32 + c4];
            xv = x4[gr * 32 + c4];
            float dv = dinv[gr];
            d2 = dv * dv;
        }
        ushort4 uu, xx;
        uu.x = f2bf(sv.x + xv.x * d2);
        uu.y = f2bf(sv.y + xv.y * d2);
        uu.z = f2bf(sv.z + xv.z * d2);
        uu.w = f2bf(sv.w + xv.w * d2);
        xx.x = f2bf(xv.x);
        xx.y = f2bf(xv.y);
        xx.z = f2bf(xv.z);
        xx.w = f2bf(xv.w);
        *reinterpret_cast<ushort4*>(&A[row * 264 + c4 * 4]) = uu;
        *reinterpret_cast<ushort4*>(&A[row * 264 + 128 + c4 * 4]) = xx;
    }
    __syncthreads();

    f32x4 acc[16];
#pragma unroll
    for (int t = 0; t < 16; ++t) acc[t] = (f32x4){0.f, 0.f, 0.f, 0.f};

    const int arow = wave * 16 + (lane & 15);
    const int koff = (lane >> 4) * 8;
    const short8* wf = reinterpret_cast<const short8*>(wfrag);

#pragma unroll
    for (int s = 0; s < 8; ++s) {
        short8 af = *reinterpret_cast<const short8*>(&A[arow * 264 + s * 32 + koff]);
#pragma unroll
        for (int t = 0; t < 16; ++t) {
            short8 bfr = wf[(s * 16 + t) * 64 + lane];
            acc[t] = __builtin_amdgcn_mfma_f32_16x16x32_bf16(af, bfr, acc[t], 0, 0, 0);
        }
    }

    // epilogue: bias, LN over 256 cols (16-lane-group reduce), gamma/beta, relu
    const int ncol = lane & 15;
    float sum[4] = {0.f, 0.f, 0.f, 0.f};
    float ssq[4] = {0.f, 0.f, 0.f, 0.f};
#pragma unroll
    for (int t = 0; t < 16; ++t) {
        float bcv = bc[t * 16 + ncol];
#pragma unroll
        for (int j = 0; j < 4; ++j) {
            float h = acc[t][j] + bcv;
            acc[t][j] = h;
            sum[j] += h;
            ssq[j] += h * h;
        }
    }
#pragma unroll
    for (int m = 1; m < 16; m <<= 1) {
#pragma unroll
        for (int j = 0; j < 4; ++j) {
            sum[j] += __shfl_xor(sum[j], m);
            ssq[j] += __shfl_xor(ssq[j], m);
        }
    }
    float mean[4], rst[4];
#pragma unroll
    for (int j = 0; j < 4; ++j) {
        mean[j] = sum[j] * (1.f / 256.f);
        float var = ssq[j] * (1.f / 256.f) - mean[j] * mean[j];
        rst[j] = rsqrtf(var + LN_EPS);
    }
    const long orow0 = r0 + wave * 16 + (lane >> 4) * 4;
#pragma unroll
    for (int t = 0; t < 16; ++t) {
        float gv = gamma[t * 16 + ncol];
        float bv = beta[t * 16 + ncol];
#pragma unroll
        for (int j = 0; j < 4; ++j) {
            long rr = orow0 + j;
            if (rr < N) {
                float o = (acc[t][j] - mean[j]) * rst[j] * gv + bv;
                out[rr * (long)OUT_C + t * 16 + ncol] = fmaxf(o, 0.f);
            }
        }
    }
}

extern "C" void kernel_launch(void* const* d_in, const int* in_sizes, int n_in,
                              void* d_out, int out_size, void* d_ws, size_t ws_size,
                              hipStream_t stream) {
    const float* x    = (const float*)d_in[0];
    const float* ew   = (const float*)d_in[1];
    const float* Wg   = (const float*)d_in[2];
    const float* bg   = (const float*)d_in[3];
    const float* Wr   = (const float*)d_in[4];
    const float* br   = (const float*)d_in[5];
    const float* gm   = (const float*)d_in[6];
    const float* bt   = (const float*)d_in[7];
    const int*   ei   = (const int*)d_in[8];

    const int N = in_sizes[0] / IN_C;
    const int E = in_sizes[8] / 2;

    // ws layout: S [N*128 f32] | deg/dinv [N f32] | wfrag [65536 bf16] | bc [256 f32]
    float* S    = (float*)d_ws;
    float* deg  = S + (size_t)N * IN_C;
    u16*   wfrag = (u16*)(deg + N);
    float* bc   = (float*)(wfrag + 65536);

    hipMemsetAsync(S, 0, (size_t)N * IN_C * sizeof(float), stream);
    k_init_deg<<<(N + 255) / 256, 256, 0, stream>>>(deg, N);
    k_wprep<<<32, 256, 0, stream>>>(Wg, Wr, bg, br, wfrag, bc);
    k_edge_deg<<<(E + 255) / 256, 256, 0, stream>>>(ei, ew, deg, E);
    k_dinv<<<(N + 255) / 256, 256, 0, stream>>>(deg, N);
    k_scatter<<<(E * 32 + 255) / 256, 256, 0, stream>>>(ei, ew, deg, (const float4*)x, S, E);
    k_gemm<<<(N + 63) / 64, 256, 0, stream>>>((const float4*)S, (const float4*)x, deg,
                                              wfrag, bc, gm, bt, (float*)d_out, N);
}

// Round 2
// 785.637 us; speedup vs baseline: 2.3343x; 2.3343x over previous
//
#include <hip/hip_runtime.h>
#include <hip/hip_bf16.h>

typedef __attribute__((ext_vector_type(8))) short short8;
typedef __attribute__((ext_vector_type(4))) float f32x4;
typedef unsigned short u16;

#define IN_C 128
#define OUT_C 256
#define LN_EPS 1e-5f

__device__ __forceinline__ u16 f2bf(float f) {
    __hip_bfloat16 h = __float2bfloat16(f);
    return __builtin_bit_cast(u16, h);
}

// deg = 1.0 (self loop), cnt = 0
__global__ void k_init(float* __restrict__ deg, int* __restrict__ cnt, int n) {
    int i = blockIdx.x * 256 + threadIdx.x;
    if (i < n) { deg[i] = 1.0f; cnt[i] = 0; }
}

// weighted degree + integer in-degree histogram
__global__ void k_count(const int* __restrict__ ei, const float* __restrict__ ew,
                        float* __restrict__ deg, int* __restrict__ cnt, int E) {
    int e = blockIdx.x * 256 + threadIdx.x;
    if (e < E) {
        int c = ei[E + e];
        atomicAdd(&deg[c], ew[e & 31]);
        atomicAdd(&cnt[c], 1);
    }
}

__global__ void k_dinv(float* __restrict__ deg, int n) {
    int i = blockIdx.x * 256 + threadIdx.x;
    if (i < n) deg[i] = rsqrtf(deg[i]);
}

// ---- exclusive scan of cnt[0..n) -> off[0..n], cur = copy ----
// level 1: per-block (1024 elems) sums
__global__ void k_scan1(const int* __restrict__ cnt, int* __restrict__ partial, int n) {
    __shared__ int sm[256];
    int b = blockIdx.x, t = threadIdx.x;
    int base = b * 1024 + t * 4;
    int s = 0;
#pragma unroll
    for (int k = 0; k < 4; ++k) { int i = base + k; if (i < n) s += cnt[i]; }
    sm[t] = s; __syncthreads();
    for (int m = 128; m > 0; m >>= 1) { if (t < m) sm[t] += sm[t + m]; __syncthreads(); }
    if (t == 0) partial[b] = sm[0];
}

// level 2: single block scans the partials (exclusive, in place). nb <= 512
__global__ void k_scan2(int* __restrict__ partial, int nb) {
    __shared__ int sm[512];
    int t = threadIdx.x;
    sm[t] = (t < nb) ? partial[t] : 0;
    __syncthreads();
    for (int d = 1; d < 512; d <<= 1) {
        int v = (t >= d) ? sm[t - d] : 0;
        __syncthreads();
        sm[t] += v;
        __syncthreads();
    }
    if (t < nb) partial[t] = (t == 0) ? 0 : sm[t - 1];
}

// level 3: final offsets (and cursor copy)
__global__ void k_scan3(const int* __restrict__ cnt, const int* __restrict__ partial,
                        int* __restrict__ off, int* __restrict__ cur, int n, int E) {
    __shared__ int sm[256];
    int b = blockIdx.x, t = threadIdx.x;
    int base = b * 1024 + t * 4;
    int c[4]; int s = 0;
#pragma unroll
    for (int k = 0; k < 4; ++k) { int i = base + k; c[k] = (i < n) ? cnt[i] : 0; s += c[k]; }
    sm[t] = s; __syncthreads();
    for (int d = 1; d < 256; d <<= 1) {
        int v = (t >= d) ? sm[t - d] : 0;
        __syncthreads();
        sm[t] += v;
        __syncthreads();
    }
    int run = partial[b] + (sm[t] - s);
#pragma unroll
    for (int k = 0; k < 4; ++k) {
        int i = base + k;
        if (i < n) { off[i] = run; cur[i] = run; }
        run += c[k];
    }
    if (b == 0 && t == 0) off[n] = E;
}

// place edge records {row, norm} grouped by target col
__global__ void k_place(const int* __restrict__ ei, const float* __restrict__ ew,
                        const float* __restrict__ dinv, int* __restrict__ cur,
                        int2* __restrict__ rec, int E) {
    int e = blockIdx.x * 256 + threadIdx.x;
    if (e >= E) return;
    int r = ei[e], c = ei[E + e];
    float nrm = dinv[r] * ew[e & 31] * dinv[c];
    int p = atomicAdd(&cur[c], 1);
    rec[p] = make_int2(r, __float_as_int(nrm));
}

// one wave per node: S[node] = x[node]*dinv^2 + sum_e norm_e * x[row_e]
__global__ __launch_bounds__(256) void k_gather(
    const float2* __restrict__ x2, const float* __restrict__ dinv,
    const int* __restrict__ off, const int2* __restrict__ rec,
    float2* __restrict__ S2, int N) {
    int wave = threadIdx.x >> 6, lane = threadIdx.x & 63;
    long node = (long)blockIdx.x * 4 + wave;
    if (node >= N) return;
    float d = dinv[node];
    float2 v0 = x2[node * 64 + lane];
    float2 acc;
    acc.x = v0.x * d * d;
    acc.y = v0.y * d * d;
    int p0 = off[node], p1 = off[node + 1];
    for (int p = p0; p < p1; ++p) {
        int2 rc = rec[p];
        float nrm = __int_as_float(rc.y);
        float2 v = x2[(long)rc.x * 64 + lane];
        acc.x += nrm * v.x;
        acc.y += nrm * v.y;
    }
    S2[node * 64 + lane] = acc;
}

// Pack Wc = [W_gcn ; W_res] (256x256) into MFMA B-fragment order (bf16), bc = b_gcn + b_res.
__global__ void k_wprep(const float* __restrict__ Wg, const float* __restrict__ Wr,
                        const float* __restrict__ bg, const float* __restrict__ br,
                        u16* __restrict__ wfrag, float* __restrict__ bc) {
    int tid = blockIdx.x * 256 + threadIdx.x;
    if (tid < OUT_C) bc[tid] = bg[tid] + br[tid];
    if (tid >= 8192) return;
    int l = tid & 63;
    int t = (tid >> 6) & 15;
    int s = tid >> 10;
    int n = t * 16 + (l & 15);
    int k0 = s * 32 + (l >> 4) * 8;
    short8 pk;
#pragma unroll
    for (int j = 0; j < 8; ++j) {
        int k = k0 + j;
        float w = (k < IN_C) ? Wg[k * OUT_C + n] : Wr[(k - IN_C) * OUT_C + n];
        pk[j] = (short)f2bf(w);
    }
    reinterpret_cast<short8*>(wfrag)[tid] = pk;
}

// Fused: h = [S | x] @ Wc + bc ; LayerNorm ; relu ; store.
__global__ __launch_bounds__(256) void k_gemm(
    const float4* __restrict__ S4, const float4* __restrict__ x4,
    const u16* __restrict__ wfrag, const float* __restrict__ bc,
    const float* __restrict__ gamma, const float* __restrict__ beta,
    float* __restrict__ out, int N) {

    __shared__ u16 A[64 * 264];  // [64 rows][256 bf16 + 8 pad] : cols 0..127 = S, 128..255 = x
    const int tid = threadIdx.x;
    const int lane = tid & 63;
    const int wave = tid >> 6;
    const long r0 = (long)blockIdx.x * 64;

#pragma unroll
    for (int i = 0; i < 8; ++i) {
        int idx = tid + i * 256;
        int row = idx >> 5;
        int c4 = idx & 31;
        long gr = r0 + row;
        float4 sv = make_float4(0.f, 0.f, 0.f, 0.f);
        float4 xv = make_float4(0.f, 0.f, 0.f, 0.f);
        if (gr < N) {
            sv = S4[gr * 32 + c4];
            xv = x4[gr * 32 + c4];
        }
        ushort4 uu, xx;
        uu.x = f2bf(sv.x); uu.y = f2bf(sv.y); uu.z = f2bf(sv.z); uu.w = f2bf(sv.w);
        xx.x = f2bf(xv.x); xx.y = f2bf(xv.y); xx.z = f2bf(xv.z); xx.w = f2bf(xv.w);
        *reinterpret_cast<ushort4*>(&A[row * 264 + c4 * 4]) = uu;
        *reinterpret_cast<ushort4*>(&A[row * 264 + 128 + c4 * 4]) = xx;
    }
    __syncthreads();

    f32x4 acc[16];
#pragma unroll
    for (int t = 0; t < 16; ++t) acc[t] = (f32x4){0.f, 0.f, 0.f, 0.f};

    const int arow = wave * 16 + (lane & 15);
    const int koff = (lane >> 4) * 8;
    const short8* wf = reinterpret_cast<const short8*>(wfrag);

#pragma unroll
    for (int s = 0; s < 8; ++s) {
        short8 af = *reinterpret_cast<const short8*>(&A[arow * 264 + s * 32 + koff]);
#pragma unroll
        for (int t = 0; t < 16; ++t) {
            short8 bfr = wf[(s * 16 + t) * 64 + lane];
            acc[t] = __builtin_amdgcn_mfma_f32_16x16x32_bf16(af, bfr, acc[t], 0, 0, 0);
        }
    }

    const int ncol = lane & 15;
    float sum[4] = {0.f, 0.f, 0.f, 0.f};
    float ssq[4] = {0.f, 0.f, 0.f, 0.f};
#pragma unroll
    for (int t = 0; t < 16; ++t) {
        float bcv = bc[t * 16 + ncol];
#pragma unroll
        for (int j = 0; j < 4; ++j) {
            float h = acc[t][j] + bcv;
            acc[t][j] = h;
            sum[j] += h;
            ssq[j] += h * h;
        }
    }
#pragma unroll
    for (int m = 1; m < 16; m <<= 1) {
#pragma unroll
        for (int j = 0; j < 4; ++j) {
            sum[j] += __shfl_xor(sum[j], m);
            ssq[j] += __shfl_xor(ssq[j], m);
        }
    }
    float mean[4], rst[4];
#pragma unroll
    for (int j = 0; j < 4; ++j) {
        mean[j] = sum[j] * (1.f / 256.f);
        float var = ssq[j] * (1.f / 256.f) - mean[j] * mean[j];
        rst[j] = rsqrtf(var + LN_EPS);
    }
    const long orow0 = r0 + wave * 16 + (lane >> 4) * 4;
#pragma unroll
    for (int t = 0; t < 16; ++t) {
        float gv = gamma[t * 16 + ncol];
        float bv = beta[t * 16 + ncol];
#pragma unroll
        for (int j = 0; j < 4; ++j) {
            long rr = orow0 + j;
            if (rr < N) {
                float o = (acc[t][j] - mean[j]) * rst[j] * gv + bv;
                out[rr * (long)OUT_C + t * 16 + ncol] = fmaxf(o, 0.f);
            }
        }
    }
}

extern "C" void kernel_launch(void* const* d_in, const int* in_sizes, int n_in,
                              void* d_out, int out_size, void* d_ws, size_t ws_size,
                              hipStream_t stream) {
    const float* x    = (const float*)d_in[0];
    const float* ew   = (const float*)d_in[1];
    const float* Wg   = (const float*)d_in[2];
    const float* bg   = (const float*)d_in[3];
    const float* Wr   = (const float*)d_in[4];
    const float* br   = (const float*)d_in[5];
    const float* gm   = (const float*)d_in[6];
    const float* bt   = (const float*)d_in[7];
    const int*   ei   = (const int*)d_in[8];

    const int N = in_sizes[0] / IN_C;
    const int E = in_sizes[8] / 2;
    const int NB1 = (N + 1023) / 1024;  // <= 512

    // ws layout
    float* S    = (float*)d_ws;                       // N*128 f32
    float* deg  = S + (size_t)N * IN_C;               // N f32 (becomes dinv)
    int*   cnt  = (int*)(deg + N);                    // N i32
    int*   off  = cnt + N;                            // N+1 i32
    int*   cur  = off + N + 1;                        // N i32
    int*   part = cur + N;                            // 512 i32
    int2*  rec  = (int2*)(part + 512);                // E int2 (8B aligned)
    u16*   wfrag = (u16*)(rec + E);                   // 65536 bf16
    float* bc   = (float*)(wfrag + 65536);            // 256 f32

    k_init<<<(N + 255) / 256, 256, 0, stream>>>(deg, cnt, N);
    k_wprep<<<32, 256, 0, stream>>>(Wg, Wr, bg, br, wfrag, bc);
    k_count<<<(E + 255) / 256, 256, 0, stream>>>(ei, ew, deg, cnt, E);
    k_dinv<<<(N + 255) / 256, 256, 0, stream>>>(deg, N);
    k_scan1<<<NB1, 256, 0, stream>>>(cnt, part, N);
    k_scan2<<<1, 512, 0, stream>>>(part, NB1);
    k_scan3<<<NB1, 256, 0, stream>>>(cnt, part, off, cur, N, E);
    k_place<<<(E + 255) / 256, 256, 0, stream>>>(ei, ew, deg, cur, rec, E);
    k_gather<<<(N + 3) / 4, 256, 0, stream>>>((const float2*)x, deg, off, rec,
                                              (float2*)S, N);
    k_gemm<<<(N + 63) / 64, 256, 0, stream>>>((const float4*)S, (const float4*)x,
                                              wfrag, bc, gm, bt, (float*)d_out, N);
}

// Round 3
// 594.946 us; speedup vs baseline: 3.0825x; 1.3205x over previous
//
#include <hip/hip_runtime.h>
#include <hip/hip_bf16.h>

typedef __attribute__((ext_vector_type(8))) short short8;
typedef __attribute__((ext_vector_type(4))) float f32x4;
typedef unsigned short u16;

#define IN_C 128
#define OUT_C 256
#define LN_EPS 1e-5f

__device__ __forceinline__ u16 f2bf(float f) {
    __hip_bfloat16 h = __float2bfloat16(f);
    return __builtin_bit_cast(u16, h);
}

// deg = 1.0 (self loop), cnt = 0
__global__ void k_init(float* __restrict__ deg, int* __restrict__ cnt, int n) {
    int i = blockIdx.x * 256 + threadIdx.x;
    if (i < n) { deg[i] = 1.0f; cnt[i] = 0; }
}

// weighted degree + integer in-degree histogram
__global__ void k_count(const int* __restrict__ ei, const float* __restrict__ ew,
                        float* __restrict__ deg, int* __restrict__ cnt, int E) {
    int e = blockIdx.x * 256 + threadIdx.x;
    if (e < E) {
        int c = ei[E + e];
        atomicAdd(&deg[c], ew[e & 31]);
        atomicAdd(&cnt[c], 1);
    }
}

__global__ void k_dinv(float* __restrict__ deg, int n) {
    int i = blockIdx.x * 256 + threadIdx.x;
    if (i < n) deg[i] = rsqrtf(deg[i]);
}

// ---- exclusive scan of cnt[0..n) -> off[0..n], cur = copy ----
__global__ void k_scan1(const int* __restrict__ cnt, int* __restrict__ partial, int n) {
    __shared__ int sm[256];
    int b = blockIdx.x, t = threadIdx.x;
    int base = b * 1024 + t * 4;
    int s = 0;
#pragma unroll
    for (int k = 0; k < 4; ++k) { int i = base + k; if (i < n) s += cnt[i]; }
    sm[t] = s; __syncthreads();
    for (int m = 128; m > 0; m >>= 1) { if (t < m) sm[t] += sm[t + m]; __syncthreads(); }
    if (t == 0) partial[b] = sm[0];
}

__global__ void k_scan2(int* __restrict__ partial, int nb) {
    __shared__ int sm[512];
    int t = threadIdx.x;
    sm[t] = (t < nb) ? partial[t] : 0;
    __syncthreads();
    for (int d = 1; d < 512; d <<= 1) {
        int v = (t >= d) ? sm[t - d] : 0;
        __syncthreads();
        sm[t] += v;
        __syncthreads();
    }
    if (t < nb) partial[t] = (t == 0) ? 0 : sm[t - 1];
}

__global__ void k_scan3(const int* __restrict__ cnt, const int* __restrict__ partial,
                        int* __restrict__ off, int* __restrict__ cur, int n, int E) {
    __shared__ int sm[256];
    int b = blockIdx.x, t = threadIdx.x;
    int base = b * 1024 + t * 4;
    int c[4]; int s = 0;
#pragma unroll
    for (int k = 0; k < 4; ++k) { int i = base + k; c[k] = (i < n) ? cnt[i] : 0; s += c[k]; }
    sm[t] = s; __syncthreads();
    for (int d = 1; d < 256; d <<= 1) {
        int v = (t >= d) ? sm[t - d] : 0;
        __syncthreads();
        sm[t] += v;
        __syncthreads();
    }
    int run = partial[b] + (sm[t] - s);
#pragma unroll
    for (int k = 0; k < 4; ++k) {
        int i = base + k;
        if (i < n) { off[i] = run; cur[i] = run; }
        run += c[k];
    }
    if (b == 0 && t == 0) off[n] = E;
}

// place edge records {row, norm} grouped by target col
__global__ void k_place(const int* __restrict__ ei, const float* __restrict__ ew,
                        const float* __restrict__ dinv, int* __restrict__ cur,
                        int2* __restrict__ rec, int E) {
    int e = blockIdx.x * 256 + threadIdx.x;
    if (e >= E) return;
    int r = ei[e], c = ei[E + e];
    float nrm = dinv[r] * ew[e & 31] * dinv[c];
    int p = atomicAdd(&cur[c], 1);
    rec[p] = make_int2(r, __float_as_int(nrm));
}

// Pack Wc = [W_gcn ; W_res] (256x256) into MFMA B-fragment order (bf16), bc = b_gcn + b_res.
__global__ void k_wprep(const float* __restrict__ Wg, const float* __restrict__ Wr,
                        const float* __restrict__ bg, const float* __restrict__ br,
                        u16* __restrict__ wfrag, float* __restrict__ bc) {
    int tid = blockIdx.x * 256 + threadIdx.x;
    if (tid < OUT_C) bc[tid] = bg[tid] + br[tid];
    if (tid >= 8192) return;
    int l = tid & 63;
    int t = (tid >> 6) & 15;
    int s = tid >> 10;
    int n = t * 16 + (l & 15);
    int k0 = s * 32 + (l >> 4) * 8;
    short8 pk;
#pragma unroll
    for (int j = 0; j < 8; ++j) {
        int k = k0 + j;
        float w = (k < IN_C) ? Wg[k * OUT_C + n] : Wr[(k - IN_C) * OUT_C + n];
        pk[j] = (short)f2bf(w);
    }
    reinterpret_cast<short8*>(wfrag)[tid] = pk;
}

// Fused: gather (u = x*dinv^2 + sum norm*x[src]) -> LDS-A ; h = [u|x]@Wc+bc ;
// LayerNorm ; relu ; store. BM=64 rows/block, 4 waves x (16 rows x 256 cols).
__global__ __launch_bounds__(256) void k_gemm(
    const float4* __restrict__ x4, const float* __restrict__ dinv,
    const int* __restrict__ off, const int2* __restrict__ rec,
    const u16* __restrict__ wfrag, const float* __restrict__ bc,
    const float* __restrict__ gamma, const float* __restrict__ beta,
    float* __restrict__ out, int N) {

    __shared__ u16 A[64 * 264];  // [64 rows][256 bf16 + 8 pad]: 0..127 = u, 128..255 = x
    const int tid = threadIdx.x;
    const int lane = tid & 63;
    const int wave = tid >> 6;
    const long r0 = (long)blockIdx.x * 64;

    // ---- fused gather staging: 4 threads per row, 32 floats each ----
    {
        const int trow = tid >> 2;   // 0..63
        const int tcol = tid & 3;    // owns floats [tcol*32, tcol*32+32)
        const long gr = r0 + trow;
        u16* up = &A[trow * 264 + tcol * 32];
        u16* xp = &A[trow * 264 + 128 + tcol * 32];
        float ua[32];
        if (gr < N) {
            float d = dinv[gr];
            float d2 = d * d;
            const float4* xs = x4 + gr * 32 + tcol * 8;
#pragma unroll
            for (int k = 0; k < 8; ++k) {
                float4 v = xs[k];
                ushort4 xx;
                xx.x = f2bf(v.x); xx.y = f2bf(v.y); xx.z = f2bf(v.z); xx.w = f2bf(v.w);
                *reinterpret_cast<ushort4*>(xp + k * 4) = xx;
                ua[4 * k + 0] = v.x * d2;
                ua[4 * k + 1] = v.y * d2;
                ua[4 * k + 2] = v.z * d2;
                ua[4 * k + 3] = v.w * d2;
            }
            const int p0 = off[gr], p1 = off[gr + 1];
            for (int p = p0; p < p1; ++p) {
                int2 rc = rec[p];
                float nrm = __int_as_float(rc.y);
                const float4* xr = x4 + (long)rc.x * 32 + tcol * 8;
#pragma unroll
                for (int k = 0; k < 8; ++k) {
                    float4 v = xr[k];
                    ua[4 * k + 0] += nrm * v.x;
                    ua[4 * k + 1] += nrm * v.y;
                    ua[4 * k + 2] += nrm * v.z;
                    ua[4 * k + 3] += nrm * v.w;
                }
            }
        } else {
#pragma unroll
            for (int k = 0; k < 32; ++k) ua[k] = 0.f;
            ushort4 zz = {0, 0, 0, 0};
#pragma unroll
            for (int k = 0; k < 8; ++k) *reinterpret_cast<ushort4*>(xp + k * 4) = zz;
        }
#pragma unroll
        for (int k = 0; k < 8; ++k) {
            ushort4 uu;
            uu.x = f2bf(ua[4 * k + 0]);
            uu.y = f2bf(ua[4 * k + 1]);
            uu.z = f2bf(ua[4 * k + 2]);
            uu.w = f2bf(ua[4 * k + 3]);
            *reinterpret_cast<ushort4*>(up + k * 4) = uu;
        }
    }
    __syncthreads();

    // ---- MFMA core ----
    f32x4 acc[16];
#pragma unroll
    for (int t = 0; t < 16; ++t) acc[t] = (f32x4){0.f, 0.f, 0.f, 0.f};

    const int arow = wave * 16 + (lane & 15);
    const int koff = (lane >> 4) * 8;
    const short8* wf = reinterpret_cast<const short8*>(wfrag);

#pragma unroll
    for (int s = 0; s < 8; ++s) {
        short8 af = *reinterpret_cast<const short8*>(&A[arow * 264 + s * 32 + koff]);
#pragma unroll
        for (int t = 0; t < 16; ++t) {
            short8 bfr = wf[(s * 16 + t) * 64 + lane];
            acc[t] = __builtin_amdgcn_mfma_f32_16x16x32_bf16(af, bfr, acc[t], 0, 0, 0);
        }
    }

    // ---- epilogue: bias, LN (16-lane-group reduce), gamma/beta, relu ----
    const int ncol = lane & 15;
    float sum[4] = {0.f, 0.f, 0.f, 0.f};
    float ssq[4] = {0.f, 0.f, 0.f, 0.f};
#pragma unroll
    for (int t = 0; t < 16; ++t) {
        float bcv = bc[t * 16 + ncol];
#pragma unroll
        for (int j = 0; j < 4; ++j) {
            float h = acc[t][j] + bcv;
            acc[t][j] = h;
            sum[j] += h;
            ssq[j] += h * h;
        }
    }
#pragma unroll
    for (int m = 1; m < 16; m <<= 1) {
#pragma unroll
        for (int j = 0; j < 4; ++j) {
            sum[j] += __shfl_xor(sum[j], m);
            ssq[j] += __shfl_xor(ssq[j], m);
        }
    }
    float mean[4], rst[4];
#pragma unroll
    for (int j = 0; j < 4; ++j) {
        mean[j] = sum[j] * (1.f / 256.f);
        float var = ssq[j] * (1.f / 256.f) - mean[j] * mean[j];
        rst[j] = rsqrtf(var + LN_EPS);
    }
    const long orow0 = r0 + wave * 16 + (lane >> 4) * 4;
#pragma unroll
    for (int t = 0; t < 16; ++t) {
        float gv = gamma[t * 16 + ncol];
        float bv = beta[t * 16 + ncol];
#pragma unroll
        for (int j = 0; j < 4; ++j) {
            long rr = orow0 + j;
            if (rr < N) {
                float o = (acc[t][j] - mean[j]) * rst[j] * gv + bv;
                out[rr * (long)OUT_C + t * 16 + ncol] = fmaxf(o, 0.f);
            }
        }
    }
}

extern "C" void kernel_launch(void* const* d_in, const int* in_sizes, int n_in,
                              void* d_out, int out_size, void* d_ws, size_t ws_size,
                              hipStream_t stream) {
    const float* x    = (const float*)d_in[0];
    const float* ew   = (const float*)d_in[1];
    const float* Wg   = (const float*)d_in[2];
    const float* bg   = (const float*)d_in[3];
    const float* Wr   = (const float*)d_in[4];
    const float* br   = (const float*)d_in[5];
    const float* gm   = (const float*)d_in[6];
    const float* bt   = (const float*)d_in[7];
    const int*   ei   = (const int*)d_in[8];

    const int N = in_sizes[0] / IN_C;
    const int E = in_sizes[8] / 2;
    const int NB1 = (N + 1023) / 1024;  // <= 512

    // ws layout (no S buffer anymore)
    float* deg  = (float*)d_ws;                       // N f32 (becomes dinv)
    int*   cnt  = (int*)(deg + N);                    // N i32
    int*   off  = cnt + N;                            // N+1 i32
    int*   cur  = off + N + 1;                        // N i32
    int*   part = cur + N;                            // 512 i32
    int2*  rec  = (int2*)(part + 512);                // E int2 (8B aligned)
    u16*   wfrag = (u16*)(rec + E);                   // 65536 bf16
    float* bc   = (float*)(wfrag + 65536);            // 256 f32

    k_init<<<(N + 255) / 256, 256, 0, stream>>>(deg, cnt, N);
    k_wprep<<<32, 256, 0, stream>>>(Wg, Wr, bg, br, wfrag, bc);
    k_count<<<(E + 255) / 256, 256, 0, stream>>>(ei, ew, deg, cnt, E);
    k_dinv<<<(N + 255) / 256, 256, 0, stream>>>(deg, N);
    k_scan1<<<NB1, 256, 0, stream>>>(cnt, part, N);
    k_scan2<<<1, 512, 0, stream>>>(part, NB1);
    k_scan3<<<NB1, 256, 0, stream>>>(cnt, part, off, cur, N, E);
    k_place<<<(E + 255) / 256, 256, 0, stream>>>(ei, ew, deg, cur, rec, E);
    k_gemm<<<(N + 63) / 64, 256, 0, stream>>>((const float4*)x, deg, off, rec,
                                              wfrag, bc, gm, bt, (float*)d_out, N);
}

// Round 4
// 549.226 us; speedup vs baseline: 3.3391x; 1.0832x over previous
//
#include <hip/hip_runtime.h>
#include <hip/hip_bf16.h>

typedef __attribute__((ext_vector_type(8))) short short8;
typedef __attribute__((ext_vector_type(4))) float f32x4;
typedef unsigned short u16;

#define IN_C 128
#define OUT_C 256
#define LN_EPS 1e-5f

__device__ __forceinline__ u16 f2bf(float f) {
    __hip_bfloat16 h = __float2bfloat16(f);
    return __builtin_bit_cast(u16, h);
}

// deg = 1.0 (self loop), cnt = 0
__global__ void k_init(float* __restrict__ deg, int* __restrict__ cnt, int n) {
    int i = blockIdx.x * 256 + threadIdx.x;
    if (i < n) { deg[i] = 1.0f; cnt[i] = 0; }
}

// weighted degree + integer in-degree histogram
__global__ void k_count(const int* __restrict__ ei, const float* __restrict__ ew,
                        float* __restrict__ deg, int* __restrict__ cnt, int E) {
    int e = blockIdx.x * 256 + threadIdx.x;
    if (e < E) {
        int c = ei[E + e];
        atomicAdd(&deg[c], ew[e & 31]);
        atomicAdd(&cnt[c], 1);
    }
}

__global__ void k_dinv(float* __restrict__ deg, int n) {
    int i = blockIdx.x * 256 + threadIdx.x;
    if (i < n) deg[i] = rsqrtf(deg[i]);
}

// ---- exclusive scan of cnt[0..n) -> off[0..n], cur = copy ----
__global__ void k_scan1(const int* __restrict__ cnt, int* __restrict__ partial, int n) {
    __shared__ int sm[256];
    int b = blockIdx.x, t = threadIdx.x;
    int base = b * 1024 + t * 4;
    int s = 0;
#pragma unroll
    for (int k = 0; k < 4; ++k) { int i = base + k; if (i < n) s += cnt[i]; }
    sm[t] = s; __syncthreads();
    for (int m = 128; m > 0; m >>= 1) { if (t < m) sm[t] += sm[t + m]; __syncthreads(); }
    if (t == 0) partial[b] = sm[0];
}

__global__ void k_scan2(int* __restrict__ partial, int nb) {
    __shared__ int sm[512];
    int t = threadIdx.x;
    sm[t] = (t < nb) ? partial[t] : 0;
    __syncthreads();
    for (int d = 1; d < 512; d <<= 1) {
        int v = (t >= d) ? sm[t - d] : 0;
        __syncthreads();
        sm[t] += v;
        __syncthreads();
    }
    if (t < nb) partial[t] = (t == 0) ? 0 : sm[t - 1];
}

__global__ void k_scan3(const int* __restrict__ cnt, const int* __restrict__ partial,
                        int* __restrict__ off, int* __restrict__ cur, int n, int E) {
    __shared__ int sm[256];
    int b = blockIdx.x, t = threadIdx.x;
    int base = b * 1024 + t * 4;
    int c[4]; int s = 0;
#pragma unroll
    for (int k = 0; k < 4; ++k) { int i = base + k; c[k] = (i < n) ? cnt[i] : 0; s += c[k]; }
    sm[t] = s; __syncthreads();
    for (int d = 1; d < 256; d <<= 1) {
        int v = (t >= d) ? sm[t - d] : 0;
        __syncthreads();
        sm[t] += v;
        __syncthreads();
    }
    int run = partial[b] + (sm[t] - s);
#pragma unroll
    for (int k = 0; k < 4; ++k) {
        int i = base + k;
        if (i < n) { off[i] = run; cur[i] = run; }
        run += c[k];
    }
    if (b == 0 && t == 0) off[n] = E;
}

// place edge records {row, norm} grouped by target col
__global__ void k_place(const int* __restrict__ ei, const float* __restrict__ ew,
                        const float* __restrict__ dinv, int* __restrict__ cur,
                        int2* __restrict__ rec, int E) {
    int e = blockIdx.x * 256 + threadIdx.x;
    if (e >= E) return;
    int r = ei[e], c = ei[E + e];
    float nrm = dinv[r] * ew[e & 31] * dinv[c];
    int p = atomicAdd(&cur[c], 1);
    rec[p] = make_int2(r, __float_as_int(nrm));
}

// Pack Wc = [W_gcn ; W_res] (256x256) into MFMA B-fragment order (bf16), bc = b_gcn + b_res.
// frag element ((s*16 + t)*64 + lane)*8 + j == Wc[k = s*32 + (lane>>4)*8 + j][n = t*16 + (lane&15)]
__global__ void k_wprep(const float* __restrict__ Wg, const float* __restrict__ Wr,
                        const float* __restrict__ bg, const float* __restrict__ br,
                        u16* __restrict__ wfrag, float* __restrict__ bc) {
    int tid = blockIdx.x * 256 + threadIdx.x;
    if (tid < OUT_C) bc[tid] = bg[tid] + br[tid];
    if (tid >= 8192) return;
    int l = tid & 63;
    int t = (tid >> 6) & 15;
    int s = tid >> 10;
    int n = t * 16 + (l & 15);
    int k0 = s * 32 + (l >> 4) * 8;
    short8 pk;
#pragma unroll
    for (int j = 0; j < 8; ++j) {
        int k = k0 + j;
        float w = (k < IN_C) ? Wg[k * OUT_C + n] : Wr[(k - IN_C) * OUT_C + n];
        pk[j] = (short)f2bf(w);
    }
    reinterpret_cast<short8*>(wfrag)[tid] = pk;
}

// Fused: gather -> LDS-A ; h = [u|x]@Wc+bc ; LayerNorm ; relu ; store.
// BM=32 rows/block, 512 threads = 8 waves; wave wv owns cols [wv*32, wv*32+32),
// holding its B-slice (16 short8) in registers for the whole block.
__global__ __launch_bounds__(512, 4) void k_gemm(
    const float4* __restrict__ x4, const float* __restrict__ dinv,
    const int* __restrict__ off, const int2* __restrict__ rec,
    const u16* __restrict__ wfrag, const float* __restrict__ bc,
    const float* __restrict__ gamma, const float* __restrict__ beta,
    float* __restrict__ out, int N) {

    __shared__ u16 A[32 * 264];          // [32 rows][256 bf16 + 8 pad]: 0..127 u, 128..255 x
    __shared__ float red[8 * 32 * 2];    // [wv][row][q] partial sum/ssq
    __shared__ float fin[32 * 2];        // final per-row sum/ssq

    const int tid = threadIdx.x;
    const int lane = tid & 63;
    const int wv = tid >> 6;             // 0..7: cols [wv*32, wv*32+32)
    const long r0 = (long)blockIdx.x * 32;

    // B-slice for this wave: s=0..7 k-slices x t=0,1 col-tiles (held in VGPRs)
    const short8* wf = reinterpret_cast<const short8*>(wfrag);
    short8 bfr[8][2];
#pragma unroll
    for (int s = 0; s < 8; ++s) {
#pragma unroll
        for (int t = 0; t < 2; ++t)
            bfr[s][t] = wf[(s * 16 + (wv * 2 + t)) * 64 + lane];
    }

    // ---- fused gather staging: 16 threads/row, 8 floats each ----
    {
        const int trow = tid >> 4;       // 0..31
        const int tq = tid & 15;         // owns floats [tq*8, tq*8+8)
        const long gr = r0 + trow;
        u16* up = &A[trow * 264 + tq * 8];
        u16* xp = &A[trow * 264 + 128 + tq * 8];
        float ua[8];
        if (gr < N) {
            float d = dinv[gr];
            float d2 = d * d;
            const float4* xs = x4 + gr * 32 + tq * 2;
            float4 v0 = xs[0], v1 = xs[1];
            ushort4 x0, x1;
            x0.x = f2bf(v0.x); x0.y = f2bf(v0.y); x0.z = f2bf(v0.z); x0.w = f2bf(v0.w);
            x1.x = f2bf(v1.x); x1.y = f2bf(v1.y); x1.z = f2bf(v1.z); x1.w = f2bf(v1.w);
            *reinterpret_cast<ushort4*>(xp) = x0;
            *reinterpret_cast<ushort4*>(xp + 4) = x1;
            ua[0] = v0.x * d2; ua[1] = v0.y * d2; ua[2] = v0.z * d2; ua[3] = v0.w * d2;
            ua[4] = v1.x * d2; ua[5] = v1.y * d2; ua[6] = v1.z * d2; ua[7] = v1.w * d2;
            const int p0 = off[gr], p1 = off[gr + 1];
            for (int p = p0; p < p1; ++p) {
                int2 rc = rec[p];
                float nrm = __int_as_float(rc.y);
                const float4* xr = x4 + (long)rc.x * 32 + tq * 2;
                float4 w0 = xr[0], w1 = xr[1];
                ua[0] += nrm * w0.x; ua[1] += nrm * w0.y;
                ua[2] += nrm * w0.z; ua[3] += nrm * w0.w;
                ua[4] += nrm * w1.x; ua[5] += nrm * w1.y;
                ua[6] += nrm * w1.z; ua[7] += nrm * w1.w;
            }
        } else {
#pragma unroll
            for (int k = 0; k < 8; ++k) ua[k] = 0.f;
            ushort4 zz = {0, 0, 0, 0};
            *reinterpret_cast<ushort4*>(xp) = zz;
            *reinterpret_cast<ushort4*>(xp + 4) = zz;
        }
        ushort4 u0, u1;
        u0.x = f2bf(ua[0]); u0.y = f2bf(ua[1]); u0.z = f2bf(ua[2]); u0.w = f2bf(ua[3]);
        u1.x = f2bf(ua[4]); u1.y = f2bf(ua[5]); u1.z = f2bf(ua[6]); u1.w = f2bf(ua[7]);
        *reinterpret_cast<ushort4*>(up) = u0;
        *reinterpret_cast<ushort4*>(up + 4) = u1;
    }
    __syncthreads();

    // ---- MFMA: each wave 32 rows x its 32 cols, B in registers ----
    f32x4 acc[2][2];
#pragma unroll
    for (int m = 0; m < 2; ++m)
#pragma unroll
        for (int t = 0; t < 2; ++t) acc[m][t] = (f32x4){0.f, 0.f, 0.f, 0.f};

    const int arowb = lane & 15;
    const int koff = (lane >> 4) * 8;
#pragma unroll
    for (int s = 0; s < 8; ++s) {
#pragma unroll
        for (int m = 0; m < 2; ++m) {
            short8 af = *reinterpret_cast<const short8*>(
                &A[(m * 16 + arowb) * 264 + s * 32 + koff]);
#pragma unroll
            for (int t = 0; t < 2; ++t)
                acc[m][t] = __builtin_amdgcn_mfma_f32_16x16x32_bf16(af, bfr[s][t], acc[m][t], 0, 0, 0);
        }
    }

    // ---- epilogue: bias, per-row partial sums over this wave's 32 cols ----
    const int ncol = lane & 15;
    const int g = lane >> 4;
    const float bc0 = bc[wv * 32 + ncol];
    const float bc1 = bc[wv * 32 + 16 + ncol];
#pragma unroll
    for (int m = 0; m < 2; ++m) {
#pragma unroll
        for (int j = 0; j < 4; ++j) {
            float v0 = acc[m][0][j] + bc0;
            float v1 = acc[m][1][j] + bc1;
            acc[m][0][j] = v0;
            acc[m][1][j] = v1;
            float s = v0 + v1;
            float q = v0 * v0 + v1 * v1;
#pragma unroll
            for (int msk = 1; msk < 16; msk <<= 1) {
                s += __shfl_xor(s, msk);
                q += __shfl_xor(q, msk);
            }
            if (ncol == 0) {
                int row = m * 16 + g * 4 + j;
                red[(wv * 32 + row) * 2 + 0] = s;
                red[(wv * 32 + row) * 2 + 1] = q;
            }
        }
    }
    __syncthreads();
    if (tid < 64) {
        int row = tid >> 1, q = tid & 1;
        float t = 0.f;
#pragma unroll
        for (int w = 0; w < 8; ++w) t += red[(w * 32 + row) * 2 + q];
        fin[row * 2 + q] = t;
    }
    __syncthreads();

    // ---- LN + relu + store ----
    const float gv0 = gamma[wv * 32 + ncol], bv0 = beta[wv * 32 + ncol];
    const float gv1 = gamma[wv * 32 + 16 + ncol], bv1 = beta[wv * 32 + 16 + ncol];
#pragma unroll
    for (int m = 0; m < 2; ++m) {
#pragma unroll
        for (int j = 0; j < 4; ++j) {
            int row = m * 16 + g * 4 + j;
            long rr = r0 + row;
            if (rr < N) {
                float mean = fin[row * 2] * (1.f / 256.f);
                float var = fin[row * 2 + 1] * (1.f / 256.f) - mean * mean;
                float rstd = rsqrtf(var + LN_EPS);
                float o0 = (acc[m][0][j] - mean) * rstd * gv0 + bv0;
                float o1 = (acc[m][1][j] - mean) * rstd * gv1 + bv1;
                float* op = out + rr * (long)OUT_C + wv * 32 + ncol;
                op[0]  = fmaxf(o0, 0.f);
                op[16] = fmaxf(o1, 0.f);
            }
        }
    }
}

extern "C" void kernel_launch(void* const* d_in, const int* in_sizes, int n_in,
                              void* d_out, int out_size, void* d_ws, size_t ws_size,
                              hipStream_t stream) {
    const float* x    = (const float*)d_in[0];
    const float* ew   = (const float*)d_in[1];
    const float* Wg   = (const float*)d_in[2];
    const float* bg   = (const float*)d_in[3];
    const float* Wr   = (const float*)d_in[4];
    const float* br   = (const float*)d_in[5];
    const float* gm   = (const float*)d_in[6];
    const float* bt   = (const float*)d_in[7];
    const int*   ei   = (const int*)d_in[8];

    const int N = in_sizes[0] / IN_C;
    const int E = in_sizes[8] / 2;
    const int NB1 = (N + 1023) / 1024;  // <= 512

    // ws layout
    float* deg  = (float*)d_ws;                       // N f32 (becomes dinv)
    int*   cnt  = (int*)(deg + N);                    // N i32
    int*   off  = cnt + N;                            // N+1 i32
    int*   cur  = off + N + 1;                        // N i32
    int*   part = cur + N;                            // 512 i32
    int2*  rec  = (int2*)(part + 512);                // E int2 (8B aligned)
    u16*   wfrag = (u16*)(rec + E);                   // 65536 bf16
    float* bc   = (float*)(wfrag + 65536);            // 256 f32

    k_init<<<(N + 255) / 256, 256, 0, stream>>>(deg, cnt, N);
    k_wprep<<<32, 256, 0, stream>>>(Wg, Wr, bg, br, wfrag, bc);
    k_count<<<(E + 255) / 256, 256, 0, stream>>>(ei, ew, deg, cnt, E);
    k_dinv<<<(N + 255) / 256, 256, 0, stream>>>(deg, N);
    k_scan1<<<NB1, 256, 0, stream>>>(cnt, part, N);
    k_scan2<<<1, 512, 0, stream>>>(part, NB1);
    k_scan3<<<NB1, 256, 0, stream>>>(cnt, part, off, cur, N, E);
    k_place<<<(E + 255) / 256, 256, 0, stream>>>(ei, ew, deg, cur, rec, E);
    k_gemm<<<(N + 31) / 32, 512, 0, stream>>>((const float4*)x, deg, off, rec,
                                              wfrag, bc, gm, bt, (float*)d_out, N);
}